// Round 11
// baseline (255.350 us; speedup 1.0000x reference)
//
#include <hip/hip_runtime.h>
#include <hip/hip_bf16.h>

// AttentionLayer: qkv = values @ w_qkv^T + b_qkv -> per-track (T=256, L=256)
// multi-head (H=8, Dh=32) softmax attention -> out = ctx @ w_lin^T + b_lin.
// I/O fp32; internals bf16 MFMA + fp32 accum.
//
// R17: kill the A-conversion pass. cvt_all (96 MB traffic, ~30 us) shrinks
// to cvt_w (weights only, 1 MB): gemm1 now reads fp32 `values` directly and
// converts during register staging (same pattern as the proven !BF B-path:
// load at loop top -> latency hides under prev tile's MFMAs -> pack -> ds_write
// after barrier). abf scratch gone. f2bf reverted to the manual bit-twiddle
// in pack paths (R16: the HIP intrinsic's NaN-checks cost ~4 us in cvt/gemm1);
// attn keeps native cvt + setprio (R16: attn-side VALUBusy 32->27.6%).
// gemm2 and attn byte-identical to R16.
// qkvb layout: [t][h][{q,k,v}][l:256][d:32] bf16; ctx overwrites the Q slot.

typedef __attribute__((ext_vector_type(8))) short short8;   // 8 bf16 (MFMA A/B frag)
typedef __attribute__((ext_vector_type(4))) float f32x4;    // MFMA C/D frag / float4

__device__ __forceinline__ unsigned short f2bf(float f) {   // manual RNE (pack paths)
    union { float f; unsigned int i; } c; c.f = f;
    unsigned int lsb = (c.i >> 16) & 1u;
    return (unsigned short)((c.i + 0x7fffu + lsb) >> 16);
}
__device__ __forceinline__ unsigned short f2bfn(float f) {  // native cvt (attn)
    union { __hip_bfloat16 h; unsigned short u; } c;
    c.h = __float2bfloat16(f);
    return c.u;
}
__device__ __forceinline__ short8 pack_bf8(f32x4 lo, f32x4 hi) {
    short8 r;
    r[0] = (short)f2bf(lo[0]); r[1] = (short)f2bf(lo[1]);
    r[2] = (short)f2bf(lo[2]); r[3] = (short)f2bf(lo[3]);
    r[4] = (short)f2bf(hi[0]); r[5] = (short)f2bf(hi[1]);
    r[6] = (short)f2bf(hi[2]); r[7] = (short)f2bf(hi[3]);
    return r;
}
__device__ __forceinline__ short8 loadB8(const unsigned short* p) { return *(const short8*)p; }
__device__ __forceinline__ short8 loadB8(const float* p) {
    return pack_bf8(*(const f32x4*)p, *(const f32x4*)(p + 4));
}
// async global->LDS, 16B/lane; LDS dest = wave-uniform base + lane*16 (HW rule)
__device__ __forceinline__ void glds16(const unsigned short* g, unsigned short* l) {
    __builtin_amdgcn_global_load_lds(
        (const __attribute__((address_space(1))) unsigned int*)g,
        (__attribute__((address_space(3))) unsigned int*)l, 16, 0, 0);
}

// fp32 -> bf16, weights only: wqkv (768x256) then wlin (256x256), 8 elems/thread.
__global__ __launch_bounds__(256)
void cvt_w(const float* __restrict__ wqkv, const float* __restrict__ wlin,
           unsigned short* __restrict__ wb)
{
    const int j = blockIdx.x * 256 + threadIdx.x;  // 0..32767
    const float* src = (j < 24576) ? wqkv + (size_t)j * 8
                                   : wlin + (size_t)(j - 24576) * 8;
    const f32x4* p = (const f32x4*)src;
    *(short8*)(wb + (size_t)j * 8) = pack_bf8(p[0], p[1]);
}

// ---- GEMM1: qkvb[t][h][w][l][d] = cvt(values) @ w_qkv^T + b_qkv ------------
// A fp32 [65536,256] register-staged + converted in-flight; Bt [768,256] bf16
// (glds) or fp32 (register-staged fallback). 128x128 tile, BK=64, 3072 blocks
// XCD-swizzled.
template <typename BT>
__global__ __launch_bounds__(256)
void gemm1_k(const float* __restrict__ A, const BT* __restrict__ Bt,
             const float* __restrict__ bias, unsigned short* __restrict__ qkvb,
             float qs)
{
    constexpr bool BF = (sizeof(BT) == 2);
    __shared__ __align__(16) unsigned short As[128 * 64];
    __shared__ __align__(16) unsigned short Bs[128 * 64];
    const int tid  = threadIdx.x;
    const int lane = tid & 63;
    const int wave = tid >> 6;
    const int wm = wave >> 1, wn = wave & 1;
    // XCD swizzle: 48-block supergroup = 8 bm x 6 bn; same-bm blocks share blk%8
    const int blk = blockIdx.x, sg = blk / 48, id = blk % 48;
    const int bm = sg * 8 + (id & 7), bn = id >> 3;
    const int fr = lane & 15, quad = lane >> 4;
    const int lr  = lane >> 3;                     // staging row within 8-group
    const int lc8 = (lane & 7) * 8;                // staging k-chunk (8 elems)

    f32x4 zz = {0.f, 0.f, 0.f, 0.f};
    f32x4 acc[4][4];
#pragma unroll
    for (int i = 0; i < 4; ++i)
#pragma unroll
        for (int j = 0; j < 4; ++j) acc[i][j] = zz;

    // A fp32 base for this thread: row bm*128 + (tid>>3) (+32i), col (tid&7)*8
    const float* Afp = A + (size_t)(bm * 128 + (tid >> 3)) * 256 + (tid & 7) * 8;

    for (int k0 = 0; k0 < 256; k0 += 64) {
        short8 av[4];                              // A: load fp32 + cvt in regs
#pragma unroll
        for (int i = 0; i < 4; ++i)
            av[i] = loadB8(Afp + (size_t)(32 * i) * 256 + k0);
        short8 bv[4];
        if constexpr (!BF) {
#pragma unroll
            for (int i = 0; i < 4; ++i)
                bv[i] = loadB8(Bt + (size_t)(bn * 128 + (tid >> 3) + 32 * i) * 256 + k0 + (tid & 7) * 8);
        }
        __syncthreads();                            // previous tile consumed
#pragma unroll
        for (int i = 0; i < 4; ++i)                 // stage A via registers
            *(short8*)&As[((tid >> 3) + 32 * i) * 64 + (tid & 7) * 8] = av[i];
        if constexpr (BF) {
#pragma unroll
            for (int i = 0; i < 4; ++i) {
                const int r0 = i * 32 + wave * 8;   // wave-uniform row group
                glds16((const unsigned short*)Bt + (size_t)(bn * 128 + r0 + lr) * 256 + k0 + lc8,
                       &Bs[r0 * 64]);
            }
        } else {
#pragma unroll
            for (int i = 0; i < 4; ++i)
                *(short8*)&Bs[((tid >> 3) + 32 * i) * 64 + (tid & 7) * 8] = bv[i];
        }
        __syncthreads();                            // staged (vmcnt+lgkm drained)
#pragma unroll
        for (int kk = 0; kk < 2; ++kk) {
            short8 a[4], b[4];
            const int qa8 = (kk * 4 + quad) * 8;
#pragma unroll
            for (int f = 0; f < 4; ++f) {
                a[f] = *(const short8*)&As[(wm * 64 + f * 16 + fr) * 64 + qa8];
                b[f] = *(const short8*)&Bs[(wn * 64 + f * 16 + fr) * 64 + qa8];
            }
#pragma unroll
            for (int fm = 0; fm < 4; ++fm)
#pragma unroll
                for (int fn = 0; fn < 4; ++fn)
                    acc[fm][fn] = __builtin_amdgcn_mfma_f32_16x16x32_bf16(
                        a[fm], b[fn], acc[fm][fn], 0, 0, 0);
        }
    }
    // epilogue -> blocked layout: col=(w,h,d), row=(t,l); C/D map m89-verified
#pragma unroll
    for (int fn = 0; fn < 4; ++fn) {
        const int col = bn * 128 + wn * 64 + fn * 16 + fr;
        const int w = col >> 8, h = (col >> 5) & 7, d = col & 31;
        const float bv2 = bias[col];
        const float s = (col < 256) ? qs : 1.0f;
#pragma unroll
        for (int fm = 0; fm < 4; ++fm) {
            const int row0 = bm * 128 + wm * 64 + fm * 16 + quad * 4;
#pragma unroll
            for (int r = 0; r < 4; ++r) {
                const int row = row0 + r;
                const int t = row >> 8, l = row & 255;
                qkvb[(size_t)(((t * 8 + h) * 3 + w)) * 8192 + l * 32 + d] =
                    f2bf((acc[fm][fn][r] + bv2) * s);
            }
        }
    }
}

// ---- GEMM2: out[65536,256] fp32 = ctx(Q slots of qkvb) @ w_lin^T + b_lin ---
template <typename BT>
__global__ __launch_bounds__(256)
void gemm2_k(const unsigned short* __restrict__ qkvb, const BT* __restrict__ Bt,
             const float* __restrict__ bias, float* __restrict__ C)
{
    constexpr bool BF = (sizeof(BT) == 2);
    __shared__ __align__(16) unsigned short As[128 * 64];
    __shared__ __align__(16) unsigned short Bs[128 * 64];
    const int tid  = threadIdx.x;
    const int lane = tid & 63;
    const int wave = tid >> 6;
    const int wm = wave >> 1, wn = wave & 1;
    // XCD swizzle: 16-block supergroup = 8 bm x 2 bn
    const int blk = blockIdx.x, sg = blk / 16, id = blk % 16;
    const int bm = sg * 8 + (id & 7), bn = id >> 3;
    const int fr = lane & 15, quad = lane >> 4;
    const int lr  = lane >> 3;
    const int lc8 = (lane & 7) * 8;
    const int t = bm >> 1;
    const int lbase = (bm & 1) * 128;

    f32x4 zz = {0.f, 0.f, 0.f, 0.f};
    f32x4 acc[4][4];
#pragma unroll
    for (int i = 0; i < 4; ++i)
#pragma unroll
        for (int j = 0; j < 4; ++j) acc[i][j] = zz;

    for (int k0 = 0; k0 < 256; k0 += 64) {
        const int kc = k0 + lc8;                   // per-lane k position
        const int h = kc >> 5, rem = kc & 31;
        const unsigned short* Ab = qkvb + (size_t)((t * 8 + h) * 3) * 8192
                                   + (size_t)(lbase + lr) * 32 + rem;
        short8 bv[4];
        if constexpr (!BF) {
#pragma unroll
            for (int i = 0; i < 4; ++i)
                bv[i] = loadB8(Bt + (size_t)(bn * 128 + (tid >> 3) + 32 * i) * 256 + k0 + (tid & 7) * 8);
        }
        __syncthreads();
#pragma unroll
        for (int i = 0; i < 4; ++i) {
            const int r0 = i * 32 + wave * 8;
            glds16(Ab + (size_t)r0 * 32, &As[r0 * 64]);
            if constexpr (BF)
                glds16((const unsigned short*)Bt + (size_t)(bn * 128 + r0 + lr) * 256 + k0 + lc8,
                       &Bs[r0 * 64]);
        }
        if constexpr (!BF) {
#pragma unroll
            for (int i = 0; i < 4; ++i)
                *(short8*)&Bs[((tid >> 3) + 32 * i) * 64 + (tid & 7) * 8] = bv[i];
        }
        __syncthreads();
#pragma unroll
        for (int kk = 0; kk < 2; ++kk) {
            short8 a[4], b[4];
            const int qa8 = (kk * 4 + quad) * 8;
#pragma unroll
            for (int f = 0; f < 4; ++f) {
                a[f] = *(const short8*)&As[(wm * 64 + f * 16 + fr) * 64 + qa8];
                b[f] = *(const short8*)&Bs[(wn * 64 + f * 16 + fr) * 64 + qa8];
            }
#pragma unroll
            for (int fm = 0; fm < 4; ++fm)
#pragma unroll
                for (int fn = 0; fn < 4; ++fn)
                    acc[fm][fn] = __builtin_amdgcn_mfma_f32_16x16x32_bf16(
                        a[fm], b[fn], acc[fm][fn], 0, 0, 0);
        }
    }
#pragma unroll
    for (int fn = 0; fn < 4; ++fn) {
        const int col = bn * 128 + wn * 64 + fn * 16 + fr;
        const float bv2 = bias[col];
#pragma unroll
        for (int fm = 0; fm < 4; ++fm) {
            const int row0 = bm * 128 + wm * 64 + fm * 16 + quad * 4;
#pragma unroll
            for (int r = 0; r < 4; ++r)
                C[(size_t)(row0 + r) * 256 + col] = acc[fm][fn][r] + bv2;
        }
    }
}

// ---- attention: one block per (t,h); contiguous 48 KB QKV slot -------------
// No-max softmax, base-2 (log2e pre-folded into Q scale): p = 2^s via
// __builtin_amdgcn_exp2f. fm-QUARTER split (R15): one fm's S-tile (16 AGPRs)
// live at a time. setprio(1) around S and PV MFMA clusters; native bf16 cvt
// (R16 attn levers). pbuf per-wave pitch 20. ctx overwrites the Q slot.
__global__ __launch_bounds__(256, 4)
void attn_kernel(unsigned short* __restrict__ qkvb)
{
    __shared__ __align__(16) unsigned short vT[32 * 264];              // 16,896 B
    __shared__ __align__(16) unsigned short pbuf[4 * 2 * 64 * 20];     // 20,480 B
    const int tid = threadIdx.x, lane = tid & 63, wave = tid >> 6;
    const int t = blockIdx.x >> 3, h = blockIdx.x & 7;
    const int fr = lane & 15, quad = lane >> 4;
    const size_t baseQ = (size_t)((t * 8 + h) * 3) * 8192;
    const size_t baseK = baseQ + 8192;
    const size_t baseV = baseQ + 16384;

    {   // stage V^T: thread tid owns v-row tid (32 bf16 = 64 B)
        const unsigned short* vp = qkvb + baseV + (size_t)tid * 32;
        short8 v0 = *(const short8*)(vp);
        short8 v1 = *(const short8*)(vp + 8);
        short8 v2 = *(const short8*)(vp + 16);
        short8 v3 = *(const short8*)(vp + 24);
#pragma unroll
        for (int d = 0; d < 8; ++d) {
            vT[(d     ) * 264 + tid] = (unsigned short)v0[d];
            vT[(d +  8) * 264 + tid] = (unsigned short)v1[d];
            vT[(d + 16) * 264 + tid] = (unsigned short)v2[d];
            vT[(d + 24) * 264 + tid] = (unsigned short)v3[d];
        }
    }
    short8 qf[4];   // Q A-frags (pre-scaled by log2e/sqrt(Dh))
#pragma unroll
    for (int fm = 0; fm < 4; ++fm)
        qf[fm] = *(const short8*)(qkvb + baseQ + (size_t)(wave * 64 + fm * 16 + fr) * 32 + quad * 8);

    __syncthreads();   // vT ready (only barrier)

    f32x4 zz = {0.f, 0.f, 0.f, 0.f};
    f32x4 O[4][2];
    float lsum[4][4];
#pragma unroll
    for (int fm = 0; fm < 4; ++fm) {
        O[fm][0] = zz; O[fm][1] = zz;
#pragma unroll
        for (int rg = 0; rg < 4; ++rg) lsum[fm][rg] = 0.f;
    }

    unsigned short* pw = pbuf + wave * (2 * 64 * 20);

    for (int jb = 0; jb < 4; ++jb) {
        const int j0 = jb * 64;
        short8 kf[4];
#pragma unroll
        for (int fn = 0; fn < 4; ++fn)
            kf[fn] = *(const short8*)(qkvb + baseK + (size_t)(j0 + fn * 16 + fr) * 32 + quad * 8);

#pragma unroll
        for (int fm = 0; fm < 4; ++fm) {           // fm-quarter: S live = 16 regs
            f32x4 S[4];
            __builtin_amdgcn_s_setprio(1);
#pragma unroll
            for (int fn = 0; fn < 4; ++fn)
                S[fn] = __builtin_amdgcn_mfma_f32_16x16x32_bf16(
                    qf[fm], kf[fn], zz, 0, 0, 0);
            __builtin_amdgcn_s_setprio(0);

#pragma unroll
            for (int kb = 0; kb < 2; ++kb) {
#pragma unroll
                for (int rg = 0; rg < 4; ++rg) {
                    const int prow = fm * 16 + quad * 4 + rg;
                    const float p0 = __builtin_amdgcn_exp2f(S[2 * kb    ][rg]);
                    const float p1 = __builtin_amdgcn_exp2f(S[2 * kb + 1][rg]);
                    lsum[fm][rg] += p0 + p1;
                    pw[          prow * 20 + fr] = f2bfn(p0);
                    pw[64 * 20 + prow * 20 + fr] = f2bfn(p1);
                }
                short8 pf = *(const short8*)&pw[(quad >> 1) * (64 * 20)
                                                + (fm * 16 + fr) * 20 + (quad & 1) * 8];
                short8 vf[2];
#pragma unroll
                for (int fd = 0; fd < 2; ++fd)
                    vf[fd] = *(const short8*)&vT[(fd * 16 + fr) * 264 + j0 + kb * 32 + quad * 8];
                __builtin_amdgcn_s_setprio(1);
                O[fm][0] = __builtin_amdgcn_mfma_f32_16x16x32_bf16(pf, vf[0], O[fm][0], 0, 0, 0);
                O[fm][1] = __builtin_amdgcn_mfma_f32_16x16x32_bf16(pf, vf[1], O[fm][1], 0, 0, 0);
                __builtin_amdgcn_s_setprio(0);
            }
        }
    }

#pragma unroll
    for (int fm = 0; fm < 4; ++fm)
#pragma unroll
        for (int rg = 0; rg < 4; ++rg) {
            float l = lsum[fm][rg];
#pragma unroll
            for (int m = 8; m >= 1; m >>= 1) l += __shfl_xor(l, m, 64);
            lsum[fm][rg] = 1.0f / l;
        }
#pragma unroll
    for (int fm = 0; fm < 4; ++fm)
#pragma unroll
        for (int fd = 0; fd < 2; ++fd)
#pragma unroll
            for (int rg = 0; rg < 4; ++rg) {
                const int row = wave * 64 + fm * 16 + quad * 4 + rg;
                const int col = fd * 16 + fr;
                qkvb[baseQ + (size_t)row * 32 + col] = f2bfn(O[fm][fd][rg] * lsum[fm][rg]);
            }
}

extern "C" void kernel_launch(void* const* d_in, const int* in_sizes, int n_in,
                              void* d_out, int out_size, void* d_ws, size_t ws_size,
                              hipStream_t stream) {
    const float* values = (const float*)d_in[0];   // [65536,256] fp32
    const float* w_qkv  = (const float*)d_in[1];   // [768,256] fp32
    const float* b_qkv  = (const float*)d_in[2];   // [768] fp32
    const float* w_lin  = (const float*)d_in[3];   // [256,256] fp32
    const float* b_lin  = (const float*)d_in[4];   // [256] fp32
    float* out = (float*)d_out;

    // 1/sqrt(32) * log2(e): softmax computed base-2 (2^s == e^{s/log2e})
    const float sc = 0.17677669529663687f * 1.4426950408889634f;
    const int N = in_sizes[0] / 256;               // 65536
    unsigned short* qkvb = (unsigned short*)d_ws;  // [256][8][3][256][32] bf16 = 96 MB
    const size_t qkvb_elems = (size_t)N * 768;
    unsigned short* wb  = qkvb + qkvb_elems;       // bf16 weights (512 KB) in ws tail
    const int wfit = (ws_size >= (qkvb_elems + 262144) * 2) ? 1 : 0;

    if (wfit) {
        cvt_w<<<dim3(128), 256, 0, stream>>>(w_qkv, w_lin, wb);
        gemm1_k<unsigned short><<<dim3(3072), 256, 0, stream>>>(values, wb, b_qkv, qkvb, sc);
        attn_kernel<<<dim3(2048), 256, 0, stream>>>(qkvb);
        gemm2_k<unsigned short><<<dim3(1024), 256, 0, stream>>>(qkvb, wb + 196608, b_lin, out);
    } else {
        gemm1_k<float><<<dim3(3072), 256, 0, stream>>>(values, w_qkv, b_qkv, qkvb, sc);
        attn_kernel<<<dim3(2048), 256, 0, stream>>>(qkvb);
        gemm2_k<float><<<dim3(1024), 256, 0, stream>>>(qkvb, w_lin, b_lin, out);
    }
}

// Round 12
// 246.837 us; speedup vs baseline: 1.0345x; 1.0345x over previous
//
#include <hip/hip_runtime.h>
#include <hip/hip_bf16.h>

// AttentionLayer: qkv = values @ w_qkv^T + b_qkv -> per-track (T=256, L=256)
// multi-head (H=8, Dh=32) softmax attention -> out = ctx @ w_lin^T + b_lin.
// I/O fp32; internals bf16 MFMA + fp32 accum.
//
// R18: compose best-known + one lever.
//  - Revert R17 fusion (gemm1 79.5us fused vs ~50 with glds-A): cvt_all +
//    glds-A gemm1 restored exactly as R15. Manual f2bf in all pack paths
//    (R16: native cvt cost ~4us there).
//  - attn: R16's proven levers kept (native f2bfn + setprio; attn 68.0) PLUS
//    pbuf 64-row -> 16-row per-fm (correctness-proven in R11; the R11 perf
//    disaster was launch_bounds(256,7) spill, not this). LDS 37,376->22,016 B
//    lifts the LDS cap 4->7 blocks/CU so the ~112-reg fm-quarter waves can
//    reach 4 blocks/CU (occupancy 35->~47%). Pitch 20, same bank pattern,
//    same in-order write->read reuse.
// qkvb layout: [t][h][{q,k,v}][l:256][d:32] bf16; ctx overwrites the Q slot.

typedef __attribute__((ext_vector_type(8))) short short8;   // 8 bf16 (MFMA A/B frag)
typedef __attribute__((ext_vector_type(4))) float f32x4;    // MFMA C/D frag / float4

__device__ __forceinline__ unsigned short f2bf(float f) {   // manual RNE (pack paths)
    union { float f; unsigned int i; } c; c.f = f;
    unsigned int lsb = (c.i >> 16) & 1u;
    return (unsigned short)((c.i + 0x7fffu + lsb) >> 16);
}
__device__ __forceinline__ unsigned short f2bfn(float f) {  // native cvt (attn)
    union { __hip_bfloat16 h; unsigned short u; } c;
    c.h = __float2bfloat16(f);
    return c.u;
}
__device__ __forceinline__ short8 pack_bf8(f32x4 lo, f32x4 hi) {
    short8 r;
    r[0] = (short)f2bf(lo[0]); r[1] = (short)f2bf(lo[1]);
    r[2] = (short)f2bf(lo[2]); r[3] = (short)f2bf(lo[3]);
    r[4] = (short)f2bf(hi[0]); r[5] = (short)f2bf(hi[1]);
    r[6] = (short)f2bf(hi[2]); r[7] = (short)f2bf(hi[3]);
    return r;
}
__device__ __forceinline__ short8 loadB8(const unsigned short* p) { return *(const short8*)p; }
__device__ __forceinline__ short8 loadB8(const float* p) {
    return pack_bf8(*(const f32x4*)p, *(const f32x4*)(p + 4));
}
// async global->LDS, 16B/lane; LDS dest = wave-uniform base + lane*16 (HW rule)
__device__ __forceinline__ void glds16(const unsigned short* g, unsigned short* l) {
    __builtin_amdgcn_global_load_lds(
        (const __attribute__((address_space(1))) unsigned int*)g,
        (__attribute__((address_space(3))) unsigned int*)l, 16, 0, 0);
}

// fp32 -> bf16: values (na8 groups of 8) then optionally both weight matrices.
__global__ __launch_bounds__(256)
void cvt_all(const float* __restrict__ values, const float* __restrict__ wqkv,
             const float* __restrict__ wlin, unsigned short* __restrict__ abf,
             unsigned short* __restrict__ wb, int na8, int do_w)
{
    const int i = blockIdx.x * 256 + threadIdx.x;
    if (i < na8) {
        const f32x4* p = (const f32x4*)values + (size_t)i * 2;
        *(short8*)(abf + (size_t)i * 8) = pack_bf8(p[0], p[1]);
    } else if (do_w) {
        const int j = i - na8;                     // 0..32767
        if (j < 32768) {
            const float* src = (j < 24576) ? wqkv + (size_t)j * 8
                                           : wlin + (size_t)(j - 24576) * 8;
            const f32x4* p = (const f32x4*)src;
            *(short8*)(wb + (size_t)j * 8) = pack_bf8(p[0], p[1]);
        }
    }
}

// ---- GEMM1: qkvb[t][h][w][l][d] = Abf @ w_qkv^T + b_qkv (Q cols scaled) ----
// A bf16 [65536,256] via global_load_lds; Bt [768,256] bf16 (glds) or fp32
// (register-staged fallback). 128x128 tile, BK=64, 3072 blocks XCD-swizzled.
template <typename BT>
__global__ __launch_bounds__(256)
void gemm1_k(const unsigned short* __restrict__ A, const BT* __restrict__ Bt,
             const float* __restrict__ bias, unsigned short* __restrict__ qkvb,
             float qs)
{
    constexpr bool BF = (sizeof(BT) == 2);
    __shared__ __align__(16) unsigned short As[128 * 64];
    __shared__ __align__(16) unsigned short Bs[128 * 64];
    const int tid  = threadIdx.x;
    const int lane = tid & 63;
    const int wave = tid >> 6;
    const int wm = wave >> 1, wn = wave & 1;
    // XCD swizzle: 48-block supergroup = 8 bm x 6 bn; same-bm blocks share blk%8
    const int blk = blockIdx.x, sg = blk / 48, id = blk % 48;
    const int bm = sg * 8 + (id & 7), bn = id >> 3;
    const int fr = lane & 15, quad = lane >> 4;
    const int lr  = lane >> 3;                     // staging row within 8-group
    const int lc8 = (lane & 7) * 8;                // staging k-chunk (8 elems)

    f32x4 zz = {0.f, 0.f, 0.f, 0.f};
    f32x4 acc[4][4];
#pragma unroll
    for (int i = 0; i < 4; ++i)
#pragma unroll
        for (int j = 0; j < 4; ++j) acc[i][j] = zz;

    const unsigned short* Ab = A + (size_t)(bm * 128 + lr) * 256 + lc8;

    for (int k0 = 0; k0 < 256; k0 += 64) {
        short8 bv[4];
        if constexpr (!BF) {
#pragma unroll
            for (int i = 0; i < 4; ++i)
                bv[i] = loadB8(Bt + (size_t)(bn * 128 + (tid >> 3) + 32 * i) * 256 + k0 + (tid & 7) * 8);
        }
        __syncthreads();                            // previous tile consumed
#pragma unroll
        for (int i = 0; i < 4; ++i) {
            const int r0 = i * 32 + wave * 8;       // wave-uniform row group
            glds16(Ab + (size_t)r0 * 256 + k0, &As[r0 * 64]);
            if constexpr (BF)
                glds16((const unsigned short*)Bt + (size_t)(bn * 128 + r0 + lr) * 256 + k0 + lc8,
                       &Bs[r0 * 64]);
        }
        if constexpr (!BF) {
#pragma unroll
            for (int i = 0; i < 4; ++i)
                *(short8*)&Bs[((tid >> 3) + 32 * i) * 64 + (tid & 7) * 8] = bv[i];
        }
        __syncthreads();                            // staged (vmcnt+lgkm drained)
#pragma unroll
        for (int kk = 0; kk < 2; ++kk) {
            short8 a[4], b[4];
            const int qa8 = (kk * 4 + quad) * 8;
#pragma unroll
            for (int f = 0; f < 4; ++f) {
                a[f] = *(const short8*)&As[(wm * 64 + f * 16 + fr) * 64 + qa8];
                b[f] = *(const short8*)&Bs[(wn * 64 + f * 16 + fr) * 64 + qa8];
            }
#pragma unroll
            for (int fm = 0; fm < 4; ++fm)
#pragma unroll
                for (int fn = 0; fn < 4; ++fn)
                    acc[fm][fn] = __builtin_amdgcn_mfma_f32_16x16x32_bf16(
                        a[fm], b[fn], acc[fm][fn], 0, 0, 0);
        }
    }
    // epilogue -> blocked layout: col=(w,h,d), row=(t,l); C/D map m89-verified
#pragma unroll
    for (int fn = 0; fn < 4; ++fn) {
        const int col = bn * 128 + wn * 64 + fn * 16 + fr;
        const int w = col >> 8, h = (col >> 5) & 7, d = col & 31;
        const float bv2 = bias[col];
        const float s = (col < 256) ? qs : 1.0f;
#pragma unroll
        for (int fm = 0; fm < 4; ++fm) {
            const int row0 = bm * 128 + wm * 64 + fm * 16 + quad * 4;
#pragma unroll
            for (int r = 0; r < 4; ++r) {
                const int row = row0 + r;
                const int t = row >> 8, l = row & 255;
                qkvb[(size_t)(((t * 8 + h) * 3 + w)) * 8192 + l * 32 + d] =
                    f2bf((acc[fm][fn][r] + bv2) * s);
            }
        }
    }
}

// ---- GEMM2: out[65536,256] fp32 = ctx(Q slots of qkvb) @ w_lin^T + b_lin ---
template <typename BT>
__global__ __launch_bounds__(256)
void gemm2_k(const unsigned short* __restrict__ qkvb, const BT* __restrict__ Bt,
             const float* __restrict__ bias, float* __restrict__ C)
{
    constexpr bool BF = (sizeof(BT) == 2);
    __shared__ __align__(16) unsigned short As[128 * 64];
    __shared__ __align__(16) unsigned short Bs[128 * 64];
    const int tid  = threadIdx.x;
    const int lane = tid & 63;
    const int wave = tid >> 6;
    const int wm = wave >> 1, wn = wave & 1;
    // XCD swizzle: 16-block supergroup = 8 bm x 2 bn
    const int blk = blockIdx.x, sg = blk / 16, id = blk % 16;
    const int bm = sg * 8 + (id & 7), bn = id >> 3;
    const int fr = lane & 15, quad = lane >> 4;
    const int lr  = lane >> 3;
    const int lc8 = (lane & 7) * 8;
    const int t = bm >> 1;
    const int lbase = (bm & 1) * 128;

    f32x4 zz = {0.f, 0.f, 0.f, 0.f};
    f32x4 acc[4][4];
#pragma unroll
    for (int i = 0; i < 4; ++i)
#pragma unroll
        for (int j = 0; j < 4; ++j) acc[i][j] = zz;

    for (int k0 = 0; k0 < 256; k0 += 64) {
        const int kc = k0 + lc8;                   // per-lane k position
        const int h = kc >> 5, rem = kc & 31;
        const unsigned short* Ab = qkvb + (size_t)((t * 8 + h) * 3) * 8192
                                   + (size_t)(lbase + lr) * 32 + rem;
        short8 bv[4];
        if constexpr (!BF) {
#pragma unroll
            for (int i = 0; i < 4; ++i)
                bv[i] = loadB8(Bt + (size_t)(bn * 128 + (tid >> 3) + 32 * i) * 256 + k0 + (tid & 7) * 8);
        }
        __syncthreads();
#pragma unroll
        for (int i = 0; i < 4; ++i) {
            const int r0 = i * 32 + wave * 8;
            glds16(Ab + (size_t)r0 * 32, &As[r0 * 64]);
            if constexpr (BF)
                glds16((const unsigned short*)Bt + (size_t)(bn * 128 + r0 + lr) * 256 + k0 + lc8,
                       &Bs[r0 * 64]);
        }
        if constexpr (!BF) {
#pragma unroll
            for (int i = 0; i < 4; ++i)
                *(short8*)&Bs[((tid >> 3) + 32 * i) * 64 + (tid & 7) * 8] = bv[i];
        }
        __syncthreads();
#pragma unroll
        for (int kk = 0; kk < 2; ++kk) {
            short8 a[4], b[4];
            const int qa8 = (kk * 4 + quad) * 8;
#pragma unroll
            for (int f = 0; f < 4; ++f) {
                a[f] = *(const short8*)&As[(wm * 64 + f * 16 + fr) * 64 + qa8];
                b[f] = *(const short8*)&Bs[(wn * 64 + f * 16 + fr) * 64 + qa8];
            }
#pragma unroll
            for (int fm = 0; fm < 4; ++fm)
#pragma unroll
                for (int fn = 0; fn < 4; ++fn)
                    acc[fm][fn] = __builtin_amdgcn_mfma_f32_16x16x32_bf16(
                        a[fm], b[fn], acc[fm][fn], 0, 0, 0);
        }
    }
#pragma unroll
    for (int fn = 0; fn < 4; ++fn) {
        const int col = bn * 128 + wn * 64 + fn * 16 + fr;
        const float bv2 = bias[col];
#pragma unroll
        for (int fm = 0; fm < 4; ++fm) {
            const int row0 = bm * 128 + wm * 64 + fm * 16 + quad * 4;
#pragma unroll
            for (int r = 0; r < 4; ++r)
                C[(size_t)(row0 + r) * 256 + col] = acc[fm][fn][r] + bv2;
        }
    }
}

// ---- attention: one block per (t,h); contiguous 48 KB QKV slot -------------
// No-max softmax, base-2 (log2e pre-folded into Q scale): p = 2^s via
// __builtin_amdgcn_exp2f. fm-QUARTER split (R15): one fm's S-tile (16 AGPRs)
// live at a time. setprio + native cvt (R16). pbuf per-fm 16-row double-plane
// (pitch 20, 5,120 B total): LDS 22,016 B lifts LDS cap to 7 blocks/CU so the
// ~112-reg waves can reach 4 blocks/CU. ctx overwrites the Q slot.
__global__ __launch_bounds__(256, 4)
void attn_kernel(unsigned short* __restrict__ qkvb)
{
    __shared__ __align__(16) unsigned short vT[32 * 264];              // 16,896 B
    __shared__ __align__(16) unsigned short pbuf[4 * 2 * 16 * 20];     //  5,120 B
    const int tid = threadIdx.x, lane = tid & 63, wave = tid >> 6;
    const int t = blockIdx.x >> 3, h = blockIdx.x & 7;
    const int fr = lane & 15, quad = lane >> 4;
    const size_t baseQ = (size_t)((t * 8 + h) * 3) * 8192;
    const size_t baseK = baseQ + 8192;
    const size_t baseV = baseQ + 16384;

    {   // stage V^T: thread tid owns v-row tid (32 bf16 = 64 B)
        const unsigned short* vp = qkvb + baseV + (size_t)tid * 32;
        short8 v0 = *(const short8*)(vp);
        short8 v1 = *(const short8*)(vp + 8);
        short8 v2 = *(const short8*)(vp + 16);
        short8 v3 = *(const short8*)(vp + 24);
#pragma unroll
        for (int d = 0; d < 8; ++d) {
            vT[(d     ) * 264 + tid] = (unsigned short)v0[d];
            vT[(d +  8) * 264 + tid] = (unsigned short)v1[d];
            vT[(d + 16) * 264 + tid] = (unsigned short)v2[d];
            vT[(d + 24) * 264 + tid] = (unsigned short)v3[d];
        }
    }
    short8 qf[4];   // Q A-frags (pre-scaled by log2e/sqrt(Dh))
#pragma unroll
    for (int fm = 0; fm < 4; ++fm)
        qf[fm] = *(const short8*)(qkvb + baseQ + (size_t)(wave * 64 + fm * 16 + fr) * 32 + quad * 8);

    __syncthreads();   // vT ready (only barrier)

    f32x4 zz = {0.f, 0.f, 0.f, 0.f};
    f32x4 O[4][2];
    float lsum[4][4];
#pragma unroll
    for (int fm = 0; fm < 4; ++fm) {
        O[fm][0] = zz; O[fm][1] = zz;
#pragma unroll
        for (int rg = 0; rg < 4; ++rg) lsum[fm][rg] = 0.f;
    }

    unsigned short* pw = pbuf + wave * (2 * 16 * 20);   // per-wave 16-row dbl-plane

    for (int jb = 0; jb < 4; ++jb) {
        const int j0 = jb * 64;
        short8 kf[4];
#pragma unroll
        for (int fn = 0; fn < 4; ++fn)
            kf[fn] = *(const short8*)(qkvb + baseK + (size_t)(j0 + fn * 16 + fr) * 32 + quad * 8);

#pragma unroll
        for (int fm = 0; fm < 4; ++fm) {           // fm-quarter: S live = 16 regs
            f32x4 S[4];
            __builtin_amdgcn_s_setprio(1);
#pragma unroll
            for (int fn = 0; fn < 4; ++fn)
                S[fn] = __builtin_amdgcn_mfma_f32_16x16x32_bf16(
                    qf[fm], kf[fn], zz, 0, 0, 0);
            __builtin_amdgcn_s_setprio(0);

#pragma unroll
            for (int kb = 0; kb < 2; ++kb) {
#pragma unroll
                for (int rg = 0; rg < 4; ++rg) {
                    const int prow = quad * 4 + rg;            // 16-row block for this fm
                    const float p0 = __builtin_amdgcn_exp2f(S[2 * kb    ][rg]);
                    const float p1 = __builtin_amdgcn_exp2f(S[2 * kb + 1][rg]);
                    lsum[fm][rg] += p0 + p1;
                    pw[          prow * 20 + fr] = f2bfn(p0);
                    pw[16 * 20 + prow * 20 + fr] = f2bfn(p1);
                }
                short8 pf = *(const short8*)&pw[(quad >> 1) * (16 * 20)
                                                + fr * 20 + (quad & 1) * 8];
                short8 vf[2];
#pragma unroll
                for (int fd = 0; fd < 2; ++fd)
                    vf[fd] = *(const short8*)&vT[(fd * 16 + fr) * 264 + j0 + kb * 32 + quad * 8];
                __builtin_amdgcn_s_setprio(1);
                O[fm][0] = __builtin_amdgcn_mfma_f32_16x16x32_bf16(pf, vf[0], O[fm][0], 0, 0, 0);
                O[fm][1] = __builtin_amdgcn_mfma_f32_16x16x32_bf16(pf, vf[1], O[fm][1], 0, 0, 0);
                __builtin_amdgcn_s_setprio(0);
            }
        }
    }

#pragma unroll
    for (int fm = 0; fm < 4; ++fm)
#pragma unroll
        for (int rg = 0; rg < 4; ++rg) {
            float l = lsum[fm][rg];
#pragma unroll
            for (int m = 8; m >= 1; m >>= 1) l += __shfl_xor(l, m, 64);
            lsum[fm][rg] = 1.0f / l;
        }
#pragma unroll
    for (int fm = 0; fm < 4; ++fm)
#pragma unroll
        for (int fd = 0; fd < 2; ++fd)
#pragma unroll
            for (int rg = 0; rg < 4; ++rg) {
                const int row = wave * 64 + fm * 16 + quad * 4 + rg;
                const int col = fd * 16 + fr;
                qkvb[baseQ + (size_t)row * 32 + col] = f2bfn(O[fm][fd][rg] * lsum[fm][rg]);
            }
}

extern "C" void kernel_launch(void* const* d_in, const int* in_sizes, int n_in,
                              void* d_out, int out_size, void* d_ws, size_t ws_size,
                              hipStream_t stream) {
    const float* values = (const float*)d_in[0];   // [65536,256] fp32
    const float* w_qkv  = (const float*)d_in[1];   // [768,256] fp32
    const float* b_qkv  = (const float*)d_in[2];   // [768] fp32
    const float* w_lin  = (const float*)d_in[3];   // [256,256] fp32
    const float* b_lin  = (const float*)d_in[4];   // [256] fp32
    float* out = (float*)d_out;

    const int N = in_sizes[0] / 256;               // 65536
    // 1/sqrt(32) * log2(e): softmax computed base-2 (2^s == e^{s/log2e})
    const float sc = 0.17677669529663687f * 1.4426950408889634f;
    unsigned short* qkvb = (unsigned short*)d_ws;  // [256][8][3][256][32] bf16 = 96 MB
    const size_t qkvb_elems = (size_t)N * 768;
    // A-bf16 scratch = front of d_out (N*256*2 B <= N*256*4 B). cvt writes it,
    // gemm1 reads it, gemm2 overwrites d_out afterwards. No cross-call state.
    unsigned short* abf = (unsigned short*)d_out;
    unsigned short* wb  = qkvb + qkvb_elems;       // bf16 weights (512 KB) in ws tail
    const int wfit = (ws_size >= (qkvb_elems + 262144) * 2) ? 1 : 0;
    const int na8 = N * 256 / 8;

    cvt_all<<<dim3((na8 + (wfit ? 32768 : 0) + 255) / 256), 256, 0, stream>>>(
        values, w_qkv, w_lin, abf, wb, na8, wfit);
    if (wfit) {
        gemm1_k<unsigned short><<<dim3(3072), 256, 0, stream>>>(abf, wb, b_qkv, qkvb, sc);
        attn_kernel<<<dim3(2048), 256, 0, stream>>>(qkvb);
        gemm2_k<unsigned short><<<dim3(1024), 256, 0, stream>>>(qkvb, wb + 196608, b_lin, out);
    } else {
        gemm1_k<float><<<dim3(3072), 256, 0, stream>>>(abf, w_qkv, b_qkv, qkvb, sc);
        attn_kernel<<<dim3(2048), 256, 0, stream>>>(qkvb);
        gemm2_k<float><<<dim3(1024), 256, 0, stream>>>(qkvb, w_lin, b_lin, out);
    }
}